// Round 6
// baseline (133.183 us; speedup 1.0000x reference)
//
#include <hip/hip_runtime.h>
#include <hip/hip_cooperative_groups.h>
#include <cstddef>

namespace cg = cooperative_groups;

// Problem constants: B=2, H=W=128, C=16, F=16, px=py=8, sx=sy=4 -> lx=ly=2
#define HH 128
#define WW 128
#define CC 16
#define NCELL 33   // cell k covers rows [4k-2, 4k+2), zero-clipped

// ---------------------------------------------------------------------------
// Shared device helper: 4x4 cell partial sums (d = sum b, k = sum pet*b)
// for cell (i,j) of batch b, channel ch, f4-group f4.
// ---------------------------------------------------------------------------
__device__ __forceinline__ void cell_sums(
    const float* __restrict__ pet, const float4* __restrict__ bfe4,
    int b, int i, int j, int ch, int f4, float4& d, float4& k)
{
    int r0 = 4 * i - 2;
    int s0 = 4 * j - 2;
    d = make_float4(0.f, 0.f, 0.f, 0.f);
    k = make_float4(0.f, 0.f, 0.f, 0.f);
    #pragma unroll
    for (int p = 0; p < 4; ++p) {
        int r = r0 + p;
        if ((unsigned)r >= (unsigned)HH) continue;
        #pragma unroll
        for (int q = 0; q < 4; ++q) {
            int s = s0 + q;
            if ((unsigned)s >= (unsigned)WW) continue;
            int pix = (b * HH + r) * WW + s;
            float4 bv = bfe4[(size_t)pix * 64 + ch * 4 + f4];
            float  pv = pet[(size_t)pix * CC + ch];
            d.x += bv.x;      d.y += bv.y;      d.z += bv.z;      d.w += bv.w;
            k.x += pv * bv.x; k.y += pv * bv.y; k.z += pv * bv.z; k.w += pv * bv.w;
        }
    }
}

// ---------------------------------------------------------------------------
// Cooperative single-dispatch kernel. 1024 blocks x 256 threads.
// Stage A: cell items 0..139391 spread over grid (each cell computed once).
// grid.sync()
// Stage B: per block one 32x16-pixel region of one (b,ch):
//   stage 7x11 cells -> LDS, 6x10 ratios -> LDS, 512 output px (2/thread).
// ---------------------------------------------------------------------------
__global__ __launch_bounds__(256, 4) void coop_kernel(
    const float*  __restrict__ pet,   // (B,128,128,16)
    const float4* __restrict__ bfe4,  // (B,128,128,16,16) as float4 over f
    float4* __restrict__ cellD,
    float4* __restrict__ cellK,
    float* __restrict__ out,          // (B,128,128,16)
    int nCellItems)
{
    __shared__ float4 sD[7 * 11 * 4];   // 4928 B
    __shared__ float4 sK[7 * 11 * 4];   // 4928 B
    __shared__ float4 sR[6 * 10 * 4];   // 3840 B

    int tid = threadIdx.x;

    // ---------------- Stage A: cells (each exactly once) ----------------
    int t = blockIdx.x * 256 + tid;
    if (t < nCellItems) {
        int f4  = t & 3;
        int ch  = (t >> 2) & 15;
        int rest = t >> 6;          // (b*33 + i)*33 + j
        int j   = rest % NCELL;
        int tmp = rest / NCELL;
        int i   = tmp % NCELL;
        int b   = tmp / NCELL;
        float4 d, k;
        cell_sums(pet, bfe4, b, i, j, ch, f4, d, k);
        cellD[t] = d;
        cellK[t] = k;
    }

    cg::this_grid().sync();

    // ---------------- Stage B: one 32x16 region per block ----------------
    int bid = blockIdx.x;
    int rx = bid & 3;            // 4 regions of 32 cols
    int ty = (bid >> 2) & 7;     // 8 regions of 16 rows
    int ch = (bid >> 5) & 15;
    int b  = bid >> 9;

    int y0 = 16 * ty, x0 = 32 * rx;
    int gi0 = 4 * ty - 1;        // 7 row-cells
    int gj0 = 8 * rx - 1;        // 11 col-cells

    // stage cells from global into LDS (zeros outside 33x33 grid)
    for (int item = tid; item < 7 * 11 * 4; item += 256) {
        int f4 = item & 3;
        int cc = item >> 2;          // ci*11+cj
        int cj = cc % 11, ci = cc / 11;
        int gi = gi0 + ci, gj = gj0 + cj;
        float4 d = make_float4(0.f, 0.f, 0.f, 0.f);
        float4 k = make_float4(0.f, 0.f, 0.f, 0.f);
        if ((unsigned)gi < (unsigned)NCELL && (unsigned)gj < (unsigned)NCELL) {
            size_t c = ((((size_t)b * NCELL + gi) * NCELL + gj) * CC + ch) * 4 + f4;
            d = cellD[c];
            k = cellK[c];
        }
        sD[item] = d;
        sK[item] = k;
    }
    __syncthreads();

    // ratios: 6x10 windows
    if (tid < 6 * 10 * 4) {
        int f4 = tid & 3;
        int pc = tid >> 2;           // pi*10+pj
        int pj = pc % 10, pi = pc / 10;
        float4 D = make_float4(0.f, 0.f, 0.f, 0.f);
        float4 K = make_float4(0.f, 0.f, 0.f, 0.f);
        #pragma unroll
        for (int di = 0; di < 2; ++di) {
            #pragma unroll
            for (int dj = 0; dj < 2; ++dj) {
                int cc = (pi + di) * 11 + (pj + dj);
                float4 cd = sD[cc * 4 + f4];
                float4 ck = sK[cc * 4 + f4];
                D.x += cd.x; D.y += cd.y; D.z += cd.z; D.w += cd.w;
                K.x += ck.x; K.y += ck.y; K.z += ck.z; K.w += ck.w;
            }
        }
        float4 rv;
        rv.x = (D.x != 0.f) ? K.x / D.x : 0.f;
        rv.y = (D.y != 0.f) ? K.y / D.y : 0.f;
        rv.z = (D.z != 0.f) ? K.z / D.z : 0.f;
        rv.w = (D.w != 0.f) ? K.w / D.w : 0.f;
        sR[tid] = rv;
    }
    __syncthreads();

    // output: 512 px, 2 per thread
    #pragma unroll
    for (int k3 = 0; k3 < 2; ++k3) {
        int p  = tid + k3 * 256;     // 0..511
        int dy = p >> 5, dx = p & 31;
        int y = y0 + dy, x = x0 + dx;

        float rs[16];
        #pragma unroll
        for (int i = 0; i < 16; ++i) rs[i] = 0.f;

        #pragma unroll
        for (int il = 0; il < 2; ++il) {
            bool vy = il ? (y >= 2) : (y <= 125);
            int pi = il ? (2 * ((dy - 2) >> 3) + 2)    // arith shift
                        : (2 * ((dy + 2) >> 3) + 1);
            #pragma unroll
            for (int jl = 0; jl < 2; ++jl) {
                bool vx = jl ? (x >= 2) : (x <= 125);
                int pj = jl ? (2 * ((dx - 2) >> 3) + 2)
                            : (2 * ((dx + 2) >> 3) + 1);
                if (vy && vx) {
                    int base = (pi * 10 + pj) * 4;
                    #pragma unroll
                    for (int v = 0; v < 4; ++v) {
                        float4 rv = sR[base + v];
                        rs[4*v+0] += rv.x; rs[4*v+1] += rv.y;
                        rs[4*v+2] += rv.z; rs[4*v+3] += rv.w;
                    }
                }
            }
        }

        int pix = (b * HH + y) * WW + x;
        const float4* bp = bfe4 + (size_t)pix * 64 + ch * 4;
        float acc = 0.f;
        #pragma unroll
        for (int v = 0; v < 4; ++v) {
            float4 bv = bp[v];
            acc += rs[4*v+0] * bv.x + rs[4*v+1] * bv.y
                 + rs[4*v+2] * bv.z + rs[4*v+3] * bv.w;
        }
        out[(size_t)pix * CC + ch] = 0.25f * acc;
    }
}

// ---------------------------------------------------------------------------
// Fallback path (proven R4 structure): K1 cells + K2 fused ratio/output.
// ---------------------------------------------------------------------------
__global__ __launch_bounds__(256) void cell_kernel(
    const float* __restrict__ pet,
    const float4* __restrict__ bfe4,
    float4* __restrict__ cellD,
    float4* __restrict__ cellK,
    int total)
{
    int t = blockIdx.x * 256 + threadIdx.x;
    if (t >= total) return;
    int f4  = t & 3;
    int ch  = (t >> 2) & 15;
    int rest = t >> 6;
    int j   = rest % NCELL;
    int tmp = rest / NCELL;
    int i   = tmp % NCELL;
    int b   = tmp / NCELL;
    float4 d, k;
    cell_sums(pet, bfe4, b, i, j, ch, f4, d, k);
    cellD[t] = d;
    cellK[t] = k;
}

__global__ __launch_bounds__(256) void fused2_kernel(
    const float4* __restrict__ bfe4,
    const float4* __restrict__ cellD,
    const float4* __restrict__ cellK,
    float* __restrict__ out)
{
    __shared__ float4 sD[7 * 7 * 4];
    __shared__ float4 sK[7 * 7 * 4];
    __shared__ float4 sR[6 * 6 * 4];

    int bid = blockIdx.x;
    int tx = bid & 7;
    int ty = (bid >> 3) & 7;
    int ch = (bid >> 6) & 15;
    int b  = bid >> 10;

    int tid = threadIdx.x;
    int y0 = 16 * ty, x0 = 16 * tx;

    if (tid < 196) {
        int f4 = tid & 3;
        int cc = tid >> 2;
        int cj = cc % 7, ci = cc / 7;
        int gi = 4 * ty - 1 + ci;
        int gj = 4 * tx - 1 + cj;
        float4 d = make_float4(0.f, 0.f, 0.f, 0.f);
        float4 k = make_float4(0.f, 0.f, 0.f, 0.f);
        if ((unsigned)gi < (unsigned)NCELL && (unsigned)gj < (unsigned)NCELL) {
            size_t c = ((((size_t)b * NCELL + gi) * NCELL + gj) * CC + ch) * 4 + f4;
            d = cellD[c];
            k = cellK[c];
        }
        sD[tid] = d;
        sK[tid] = k;
    }
    __syncthreads();

    if (tid < 144) {
        int f4 = tid & 3;
        int pc = tid >> 2;
        int pj = pc % 6, pi = pc / 6;
        float4 D = make_float4(0.f, 0.f, 0.f, 0.f);
        float4 K = make_float4(0.f, 0.f, 0.f, 0.f);
        #pragma unroll
        for (int di = 0; di < 2; ++di) {
            #pragma unroll
            for (int dj = 0; dj < 2; ++dj) {
                int cc = (pi + di) * 7 + (pj + dj);
                float4 cd = sD[cc * 4 + f4];
                float4 ck = sK[cc * 4 + f4];
                D.x += cd.x; D.y += cd.y; D.z += cd.z; D.w += cd.w;
                K.x += ck.x; K.y += ck.y; K.z += ck.z; K.w += ck.w;
            }
        }
        float4 rv;
        rv.x = (D.x != 0.f) ? K.x / D.x : 0.f;
        rv.y = (D.y != 0.f) ? K.y / D.y : 0.f;
        rv.z = (D.z != 0.f) ? K.z / D.z : 0.f;
        rv.w = (D.w != 0.f) ? K.w / D.w : 0.f;
        sR[pc * 4 + f4] = rv;
    }
    __syncthreads();

    int dy = tid >> 4, dx = tid & 15;
    int y = y0 + dy, x = x0 + dx;

    float rs[16];
    #pragma unroll
    for (int i = 0; i < 16; ++i) rs[i] = 0.f;

    #pragma unroll
    for (int il = 0; il < 2; ++il) {
        bool vy = il ? (y >= 2) : (y <= 125);
        int pi = il ? (2 * ((dy - 2) >> 3) + 2)
                    : (2 * ((dy + 2) >> 3) + 1);
        #pragma unroll
        for (int jl = 0; jl < 2; ++jl) {
            bool vx = jl ? (x >= 2) : (x <= 125);
            int pj = jl ? (2 * ((dx - 2) >> 3) + 2)
                        : (2 * ((dx + 2) >> 3) + 1);
            if (vy && vx) {
                int base = (pi * 6 + pj) * 4;
                #pragma unroll
                for (int v = 0; v < 4; ++v) {
                    float4 rv = sR[base + v];
                    rs[4*v+0] += rv.x; rs[4*v+1] += rv.y;
                    rs[4*v+2] += rv.z; rs[4*v+3] += rv.w;
                }
            }
        }
    }

    int pix = (b * HH + y) * WW + x;
    const float4* bp = bfe4 + (size_t)pix * 64 + ch * 4;
    float acc = 0.f;
    #pragma unroll
    for (int v = 0; v < 4; ++v) {
        float4 bv = bp[v];
        acc += rs[4*v+0] * bv.x + rs[4*v+1] * bv.y
             + rs[4*v+2] * bv.z + rs[4*v+3] * bv.w;
    }
    out[(size_t)pix * CC + ch] = 0.25f * acc;
}

extern "C" void kernel_launch(void* const* d_in, const int* in_sizes, int n_in,
                              void* d_out, int out_size, void* d_ws, size_t ws_size,
                              hipStream_t stream) {
    // inputs: 0=mr (unused), 1=pet (B,128,128,16), 2=b_features (B,128,128,16,16)
    const float* pet = (const float*)d_in[1];
    const float4* bfe4 = (const float4*)d_in[2];
    int B = in_sizes[1] / (HH * WW * CC);   // = 2

    int nCellItems = B * NCELL * NCELL * CC * 4;   // 139392 float4 items
    float4* cellD = (float4*)d_ws;
    float4* cellK = cellD + nCellItems;
    float* outp = (float*)d_out;

    // Cooperative single dispatch: 1024 blocks (B*16*32 regions), 256 threads.
    int grid = B * 16 * 32;                  // 1024
    void* args[] = { (void*)&pet, (void*)&bfe4, (void*)&cellD, (void*)&cellK,
                     (void*)&outp, (void*)&nCellItems };
    hipError_t e = hipLaunchCooperativeKernel(
        (const void*)coop_kernel, dim3(grid), dim3(256), args, 0, stream);

    if (e != hipSuccess) {
        // Fallback: proven two-kernel path (R4).
        (void)hipGetLastError();  // clear error state
        int gA = (nCellItems + 255) / 256;   // 545 blocks
        cell_kernel<<<gA, 256, 0, stream>>>(pet, bfe4, cellD, cellK, nCellItems);
        int gC = B * 16 * 64;                // 2048 blocks
        fused2_kernel<<<gC, 256, 0, stream>>>(bfe4, cellD, cellK, outp);
    }
}

// Round 7
// 29.335 us; speedup vs baseline: 4.5401x; 4.5401x over previous
//
#include <hip/hip_runtime.h>
#include <cstddef>

// Problem constants: B=2, H=W=128, C=16, F=16, px=py=8, sx=sy=4 -> lx=ly=2
#define HH 128
#define WW 128
#define CC 16

#define ADD4(a, v) { (a).x += (v).x; (a).y += (v).y; (a).z += (v).z; (a).w += (v).w; }
#define FMA4(a, s, v) { (a).x += (s)*(v).x; (a).y += (s)*(v).y; (a).z += (s)*(v).z; (a).w += (s)*(v).w; }

// Single-dispatch fused kernel. Block = (b, ch-pair, 16x16 pixel tile).
// 1024 blocks x 256 threads (4 blocks/CU -> 16 waves/CU), LDS 17.2 KB.
//
// Phase 1: 7x7 halo cells x (2ch x 4 f4) = 392 items -> LDS.
//   Cell (gi,gj) covers rows [4gi-2,4gi+2) x cols [4gj-2,4gj+2), zero-clipped.
//   Wave pattern: 8 consecutive lanes = one cell's 8 (ch2,f4) combos ->
//   128B fully-utilized chunk per pixel (this is the fix for R3's 4KB-stride gather).
// Phase 2: 6x6 patch ratios x 8 combos = 288 items (divide_no_nan) -> LDS.
// Phase 3: 512 outputs (16x16 px x 2 ch), 2/thread, ch2-fastest lanes ->
//   bfe loads land as 128B chunks.
__global__ __launch_bounds__(256) void fused_cp_kernel(
    const float*  __restrict__ pet,   // (B,128,128,16)
    const float4* __restrict__ bfe4,  // (B,128,128,16,16) as float4 over f
    float* __restrict__ out)          // (B,128,128,16)
{
    __shared__ float4 sD[49 * 8];   // 6272 B
    __shared__ float4 sK[49 * 8];   // 6272 B
    __shared__ float4 sR[36 * 8];   // 4608 B

    int bid = blockIdx.x;
    int tx = bid & 7;
    int ty = (bid >> 3) & 7;
    int cp = (bid >> 6) & 7;
    int b  = bid >> 9;
    int chb = cp * 2;

    int tid = threadIdx.x;
    int y0 = 16 * ty, x0 = 16 * tx;
    int gi0 = 4 * ty - 1, gj0 = 4 * tx - 1;   // cell-grid origin (halo)

    // ---------------- Phase 1: halo cells, coalesced ----------------
    for (int item = tid; item < 392; item += 256) {
        int e   = item & 7;          // (ch2,f4)
        int f4  = e & 3;
        int ch2 = e >> 2;
        int cc  = item >> 3;         // 0..48
        int ci  = cc / 7, cj = cc % 7;
        int r0 = 4 * (gi0 + ci) - 2;
        int s0 = 4 * (gj0 + cj) - 2;
        float4 d = make_float4(0.f, 0.f, 0.f, 0.f);
        float4 k = make_float4(0.f, 0.f, 0.f, 0.f);
        #pragma unroll
        for (int p = 0; p < 4; ++p) {
            int r = r0 + p;
            if ((unsigned)r >= (unsigned)HH) continue;
            #pragma unroll
            for (int q = 0; q < 4; ++q) {
                int s = s0 + q;
                if ((unsigned)s >= (unsigned)WW) continue;
                int pix = (b * HH + r) * WW + s;
                float4 bv = bfe4[(size_t)pix * 64 + (chb + ch2) * 4 + f4];
                float  pv = pet[(size_t)pix * CC + chb + ch2];
                ADD4(d, bv);
                FMA4(k, pv, bv);
            }
        }
        sD[item] = d;
        sK[item] = k;
    }
    __syncthreads();

    // ---------------- Phase 2: ratios ----------------
    for (int item = tid; item < 288; item += 256) {
        int e  = item & 7;
        int pc = item >> 3;          // 0..35
        int pj = pc % 6, pi = pc / 6;
        float4 D = make_float4(0.f, 0.f, 0.f, 0.f);
        float4 K = make_float4(0.f, 0.f, 0.f, 0.f);
        #pragma unroll
        for (int di = 0; di < 2; ++di) {
            #pragma unroll
            for (int dj = 0; dj < 2; ++dj) {
                int c = ((pi + di) * 7 + (pj + dj)) * 8 + e;
                float4 cd = sD[c];
                float4 ck = sK[c];
                ADD4(D, cd);
                ADD4(K, ck);
            }
        }
        float4 rv;
        rv.x = (D.x != 0.f) ? K.x / D.x : 0.f;
        rv.y = (D.y != 0.f) ? K.y / D.y : 0.f;
        rv.z = (D.z != 0.f) ? K.z / D.z : 0.f;
        rv.w = (D.w != 0.f) ? K.w / D.w : 0.f;
        sR[item] = rv;
    }
    __syncthreads();

    // ---------------- Phase 3: output, 2 per thread, ch2-fastest ----------------
    #pragma unroll
    for (int kk = 0; kk < 2; ++kk) {
        int o   = tid + kk * 256;    // 0..511
        int ch2 = o & 1;
        int dx  = (o >> 1) & 15;
        int dy  = o >> 5;
        int y = y0 + dy, x = x0 + dx;

        float4 rs0 = make_float4(0.f, 0.f, 0.f, 0.f);
        float4 rs1 = make_float4(0.f, 0.f, 0.f, 0.f);
        float4 rs2 = make_float4(0.f, 0.f, 0.f, 0.f);
        float4 rs3 = make_float4(0.f, 0.f, 0.f, 0.f);

        #pragma unroll
        for (int il = 0; il < 2; ++il) {
            bool vy = il ? (y >= 2) : (y <= 125);
            int pi = il ? (2 * ((dy - 2) >> 3) + 2)    // arithmetic shift
                        : (2 * ((dy + 2) >> 3) + 1);
            #pragma unroll
            for (int jl = 0; jl < 2; ++jl) {
                bool vx = jl ? (x >= 2) : (x <= 125);
                int pj = jl ? (2 * ((dx - 2) >> 3) + 2)
                            : (2 * ((dx + 2) >> 3) + 1);
                if (vy && vx) {
                    int base = (pi * 6 + pj) * 8 + ch2 * 4;
                    ADD4(rs0, sR[base + 0]);
                    ADD4(rs1, sR[base + 1]);
                    ADD4(rs2, sR[base + 2]);
                    ADD4(rs3, sR[base + 3]);
                }
            }
        }

        int pix = (b * HH + y) * WW + x;
        const float4* bp = bfe4 + (size_t)pix * 64 + (chb + ch2) * 4;
        float4 b0 = bp[0], b1 = bp[1], b2 = bp[2], b3 = bp[3];
        float acc =
            rs0.x * b0.x + rs0.y * b0.y + rs0.z * b0.z + rs0.w * b0.w +
            rs1.x * b1.x + rs1.y * b1.y + rs1.z * b1.z + rs1.w * b1.w +
            rs2.x * b2.x + rs2.y * b2.y + rs2.z * b2.z + rs2.w * b2.w +
            rs3.x * b3.x + rs3.y * b3.y + rs3.z * b3.z + rs3.w * b3.w;
        out[(size_t)pix * CC + chb + ch2] = 0.25f * acc;
    }
}

extern "C" void kernel_launch(void* const* d_in, const int* in_sizes, int n_in,
                              void* d_out, int out_size, void* d_ws, size_t ws_size,
                              hipStream_t stream) {
    // inputs: 0=mr (unused), 1=pet (B,128,128,16), 2=b_features (B,128,128,16,16)
    const float* pet = (const float*)d_in[1];
    const float4* bfe4 = (const float4*)d_in[2];
    int B = in_sizes[1] / (HH * WW * CC);   // = 2

    // grid: b * 8 ch-pairs * (8x8 tiles of 16x16) = B*512 = 1024
    int grid = B * 8 * 64;
    fused_cp_kernel<<<grid, 256, 0, stream>>>(pet, bfe4, (float*)d_out);
}

// Round 8
// 23.323 us; speedup vs baseline: 5.7104x; 1.2578x over previous
//
#include <hip/hip_runtime.h>
#include <cstddef>

// Problem constants: B=2, H=W=128, C=16, F=16, px=py=8, sx=sy=4 -> lx=ly=2
#define HH 128
#define WW 128
#define CC 16
#define NCELL 33   // cell k covers rows [4k-2, 4k+2), zero-clipped

// ---------------------------------------------------------------------------
// cell partial sums (d = sum b, k = sum pet*b) for cell (i,j), channel ch, f4
// ---------------------------------------------------------------------------
__device__ __forceinline__ void cell_sums(
    const float* __restrict__ pet, const float4* __restrict__ bfe4,
    int b, int i, int j, int ch, int f4, float4& d, float4& k)
{
    int r0 = 4 * i - 2;
    int s0 = 4 * j - 2;
    d = make_float4(0.f, 0.f, 0.f, 0.f);
    k = make_float4(0.f, 0.f, 0.f, 0.f);
    #pragma unroll
    for (int p = 0; p < 4; ++p) {
        int r = r0 + p;
        if ((unsigned)r >= (unsigned)HH) continue;
        #pragma unroll
        for (int q = 0; q < 4; ++q) {
            int s = s0 + q;
            if ((unsigned)s >= (unsigned)WW) continue;
            int pix = (b * HH + r) * WW + s;
            float4 bv = bfe4[(size_t)pix * 64 + ch * 4 + f4];
            float  pv = pet[(size_t)pix * CC + ch];
            d.x += bv.x;      d.y += bv.y;      d.z += bv.z;      d.w += bv.w;
            k.x += pv * bv.x; k.y += pv * bv.y; k.z += pv * bv.z; k.w += pv * bv.w;
        }
    }
}

// ---------------------------------------------------------------------------
// K1: cells, XCD-aligned. Block covers a 4-cell j-strip (j = 4*jg .. 4*jg+3)
// of one cell-row i of one batch. bid%8 == jg%8 == the pixel-column tile tx
// that K2 blocks for the same columns use -> same XCD, so K2's bfe re-read
// hits that XCD's L2.
//   bid = ((b*33 + i)*2 + (jg>>3))*8 + (jg&7); jg in [0,9) valid.
// Thread: lanes 0..63 = all (ch,f4) of one cell -> contiguous 1KB loads
// (the proven R4 coalescing unit). tid>>6 = local cell 0..3.
// ---------------------------------------------------------------------------
__global__ __launch_bounds__(256) void cell_kernel_x(
    const float* __restrict__ pet,
    const float4* __restrict__ bfe4,
    float4* __restrict__ cellD,
    float4* __restrict__ cellK)
{
    int bid = blockIdx.x;
    int xcd  = bid & 7;
    int hi   = bid >> 3;       // (b*33 + i)*2 + jh
    int jh   = hi & 1;
    int rest = hi >> 1;        // b*33 + i
    int i = rest % NCELL;
    int b = rest / NCELL;
    int jg = jh * 8 + xcd;     // 0..15; valid jg < 9
    if (jg >= 9) return;

    int lc = threadIdx.x >> 6;       // local cell 0..3
    int j  = jg * 4 + lc;
    if (j >= NCELL) return;          // only jg==8, lc>0

    int e  = threadIdx.x & 63;       // ch*4 + f4
    int ch = e >> 2;
    int f4 = e & 3;

    float4 d, k;
    cell_sums(pet, bfe4, b, i, j, ch, f4, d, k);

    size_t t = ((((size_t)b * NCELL + i) * NCELL + j) * CC + ch) * 4 + f4;
    cellD[t] = d;
    cellK[t] = k;
}

// ---------------------------------------------------------------------------
// K2: fused ratio + output (identical to R4's proven fused2_kernel).
// Block = (b, ch, 16x16 tile); bid%8 = tx -> XCD matches K1's jg.
// ---------------------------------------------------------------------------
__global__ __launch_bounds__(256) void fused2_kernel(
    const float4* __restrict__ bfe4,
    const float4* __restrict__ cellD,
    const float4* __restrict__ cellK,
    float* __restrict__ out)
{
    __shared__ float4 sD[7 * 7 * 4];
    __shared__ float4 sK[7 * 7 * 4];
    __shared__ float4 sR[6 * 6 * 4];

    int bid = blockIdx.x;
    int tx = bid & 7;
    int ty = (bid >> 3) & 7;
    int ch = (bid >> 6) & 15;
    int b  = bid >> 10;

    int tid = threadIdx.x;
    int y0 = 16 * ty, x0 = 16 * tx;

    // stage 7x7 halo cells from global (zeros outside the 33x33 grid)
    if (tid < 196) {
        int f4 = tid & 3;
        int cc = tid >> 2;
        int cj = cc % 7, ci = cc / 7;
        int gi = 4 * ty - 1 + ci;
        int gj = 4 * tx - 1 + cj;
        float4 d = make_float4(0.f, 0.f, 0.f, 0.f);
        float4 k = make_float4(0.f, 0.f, 0.f, 0.f);
        if ((unsigned)gi < (unsigned)NCELL && (unsigned)gj < (unsigned)NCELL) {
            size_t c = ((((size_t)b * NCELL + gi) * NCELL + gj) * CC + ch) * 4 + f4;
            d = cellD[c];
            k = cellK[c];
        }
        sD[tid] = d;
        sK[tid] = k;
    }
    __syncthreads();

    // 6x6 ratios (divide_no_nan of 2x2-cell window sums)
    if (tid < 144) {
        int f4 = tid & 3;
        int pc = tid >> 2;
        int pj = pc % 6, pi = pc / 6;
        float4 D = make_float4(0.f, 0.f, 0.f, 0.f);
        float4 K = make_float4(0.f, 0.f, 0.f, 0.f);
        #pragma unroll
        for (int di = 0; di < 2; ++di) {
            #pragma unroll
            for (int dj = 0; dj < 2; ++dj) {
                int cc = (pi + di) * 7 + (pj + dj);
                float4 cd = sD[cc * 4 + f4];
                float4 ck = sK[cc * 4 + f4];
                D.x += cd.x; D.y += cd.y; D.z += cd.z; D.w += cd.w;
                K.x += ck.x; K.y += ck.y; K.z += ck.z; K.w += ck.w;
            }
        }
        float4 rv;
        rv.x = (D.x != 0.f) ? K.x / D.x : 0.f;
        rv.y = (D.y != 0.f) ? K.y / D.y : 0.f;
        rv.z = (D.z != 0.f) ? K.z / D.z : 0.f;
        rv.w = (D.w != 0.f) ? K.w / D.w : 0.f;
        sR[pc * 4 + f4] = rv;
    }
    __syncthreads();

    // output: one pixel per thread
    int dy = tid >> 4, dx = tid & 15;
    int y = y0 + dy, x = x0 + dx;

    float rs[16];
    #pragma unroll
    for (int i = 0; i < 16; ++i) rs[i] = 0.f;

    #pragma unroll
    for (int il = 0; il < 2; ++il) {
        bool vy = il ? (y >= 2) : (y <= 125);
        int pi = il ? (2 * ((dy - 2) >> 3) + 2)    // arithmetic shift
                    : (2 * ((dy + 2) >> 3) + 1);
        #pragma unroll
        for (int jl = 0; jl < 2; ++jl) {
            bool vx = jl ? (x >= 2) : (x <= 125);
            int pj = jl ? (2 * ((dx - 2) >> 3) + 2)
                        : (2 * ((dx + 2) >> 3) + 1);
            if (vy && vx) {
                int base = (pi * 6 + pj) * 4;
                #pragma unroll
                for (int v = 0; v < 4; ++v) {
                    float4 rv = sR[base + v];
                    rs[4*v+0] += rv.x; rs[4*v+1] += rv.y;
                    rs[4*v+2] += rv.z; rs[4*v+3] += rv.w;
                }
            }
        }
    }

    int pix = (b * HH + y) * WW + x;
    const float4* bp = bfe4 + (size_t)pix * 64 + ch * 4;
    float acc = 0.f;
    #pragma unroll
    for (int v = 0; v < 4; ++v) {
        float4 bv = bp[v];
        acc += rs[4*v+0] * bv.x + rs[4*v+1] * bv.y
             + rs[4*v+2] * bv.z + rs[4*v+3] * bv.w;
    }
    out[(size_t)pix * CC + ch] = 0.25f * acc;
}

extern "C" void kernel_launch(void* const* d_in, const int* in_sizes, int n_in,
                              void* d_out, int out_size, void* d_ws, size_t ws_size,
                              hipStream_t stream) {
    // inputs: 0=mr (unused), 1=pet (B,128,128,16), 2=b_features (B,128,128,16,16)
    const float* pet = (const float*)d_in[1];
    const float4* bfe4 = (const float4*)d_in[2];
    int B = in_sizes[1] / (HH * WW * CC);   // = 2

    int nCellVec = B * NCELL * NCELL * CC * 4;   // 139392 float4 for B=2
    float4* cellD = (float4*)d_ws;
    float4* cellK = cellD + nCellVec;

    // K1: XCD-aligned cell kernel. grid = B*33*2*8 (some blocks exit early).
    int g1 = B * NCELL * 2 * 8;              // 1056 for B=2
    cell_kernel_x<<<g1, 256, 0, stream>>>(pet, bfe4, cellD, cellK);

    // K2: fused ratio+output, bid%8 = tile column = same XCD as K1.
    int g2 = B * 16 * 64;                    // 2048
    fused2_kernel<<<g2, 256, 0, stream>>>(bfe4, cellD, cellK, (float*)d_out);
}